// Round 14
// baseline (641.083 us; speedup 1.0000x reference)
//
#include <hip/hip_runtime.h>

typedef unsigned short u16;
typedef short bf16x8 __attribute__((ext_vector_type(8)));
typedef float f32x4 __attribute__((ext_vector_type(4)));

#define BSZ 8192
#define OUTLD 7168

__device__ __forceinline__ u16 f2bf(float f) {
  union { float f; unsigned u; } v; v.f = f;
  unsigned r = v.u + 0x7FFFu + ((v.u >> 16) & 1u);
  return (u16)(r >> 16);
}
__device__ __forceinline__ float bf2f(u16 h) {
  union { unsigned u; float f; } v; v.u = ((unsigned)h) << 16;
  return v.f;
}
__device__ __forceinline__ float sigmoidf_(float x) { return 1.0f / (1.0f + __expf(-x)); }
__device__ __forceinline__ float tanhf_(float t) { return 2.0f / (1.0f + __expf(-2.0f * t)) - 1.0f; }

__device__ __forceinline__ void gload16(const u16* g, u16* l) {
  __builtin_amdgcn_global_load_lds(
      (const __attribute__((address_space(1))) void*)g,
      (__attribute__((address_space(3))) void*)l, 16, 0, 0);
}

// ======== fused front-end: weight cvt + gru perm-cvt + input prep + ae ========
struct FuseArgs {
  const float* cs[5]; u16* cd[5]; long cn[5];          // plain cvt segments (float4 units)
  const float* sIh; u16* dIh; const float* sHh; u16* dHh;
  const float* ps[3]; u16* pd[3]; long pn[3]; int pc4[3]; int pdoR[3];
  const float* act; const float* Wact; const float* bact; u16* xout;
  const void* isf;
};

__global__ void k_fuse(FuseArgs a) {
  // inline is_first dtype detect (bool8 vs int32/f32), 8KB scan per block (L2-hot)
  __shared__ unsigned redS;
  if (threadIdx.x == 0) redS = 0u;
  __syncthreads();
  {
    unsigned v = 0;
    const unsigned* w = (const unsigned*)a.isf;
    for (int i = threadIdx.x; i < 2048; i += 256) v |= w[i];
    atomicOr(&redS, v);
  }
  __syncthreads();
  const int fl = (((redS & 0xFFFFFF00u) != 0u) && ((redS & 0xFEFEFEFEu) == 0u)) ? 1 : 0;

  const long B0 = 3145728L;                 // end cvtW
  const long B1 = B0 + 1179648L;            // end gruW (8-elem units)
  const long B2 = B1 + 12582912L;           // end prep (float4 units)
  const long B3 = B2 + 2097152L;            // end ae (4-h units)
  const long nIh = 393216L;

  long stride = (long)gridDim.x * blockDim.x;
  for (long i = blockIdx.x * (long)blockDim.x + threadIdx.x; i < B3; i += stride) {
    if (i < B0) {
      long rem = i; int k = 0;
      while (k < 4 && rem >= a.cn[k]) { rem -= a.cn[k]; ++k; }
      float4 v = ((const float4*)a.cs[k])[rem];
      ushort4 o; o.x = f2bf(v.x); o.y = f2bf(v.y); o.z = f2bf(v.z); o.w = f2bf(v.w);
      ((ushort4*)a.cd[k])[rem] = o;
    } else if (i < B1) {
      long rel = i - B0;
      const float* src; u16* dst; int ldk;
      if (rel < nIh) { src = a.sIh; dst = a.dIh; ldk = 256; }
      else           { src = a.sHh; dst = a.dHh; ldk = 512; rel -= nIh; }
      int kc = ldk >> 3;
      int j = (int)(rel % kc); long row = rel / kc;
      long blk = row / 1536; int rP = (int)(row % 1536);
      int sHi = rP / 48, rem = rP % 48, g = rem >> 4, sLo = rem & 15;
      int srow = g * 512 + sHi * 16 + sLo;
      const float* s = src + (blk * 1536 + srow) * (long)ldk + j * 8;
      float4 v0 = ((const float4*)s)[0], v1 = ((const float4*)s)[1];
      ushort4 o0; o0.x = f2bf(v0.x); o0.y = f2bf(v0.y); o0.z = f2bf(v0.z); o0.w = f2bf(v0.w);
      ushort4 o1; o1.x = f2bf(v1.x); o1.y = f2bf(v1.y); o1.z = f2bf(v1.z); o1.w = f2bf(v1.w);
      ((ushort4*)(dst + rel * 8))[0] = o0;
      ((ushort4*)(dst + rel * 8))[1] = o1;
    } else if (i < B2) {
      long rel = i - B1; int k = 0;
      while (k < 2 && rel >= a.pn[k]) { rel -= a.pn[k]; ++k; }
      float4 v = ((const float4*)a.ps[k])[rel];
      if (a.pdoR[k]) {
        int b = (int)(rel / a.pc4[k]);
        bool isf1 = fl ? (((const unsigned char*)a.isf)[b] != 0)
                       : (((const int*)a.isf)[b] != 0);
        if (isf1) { v.x = v.y = v.z = v.w = 0.f; }
      }
      ushort4 o; o.x = f2bf(v.x); o.y = f2bf(v.y); o.z = f2bf(v.z); o.w = f2bf(v.w);
      ((ushort4*)a.pd[k])[rel] = o;
    } else {
      long t = i - B2;
      int b = (int)(t >> 8), h0 = (int)(t & 255) * 4;
      float4 a0 = ((const float4*)a.act)[b * 2];
      float4 a1 = ((const float4*)a.act)[b * 2 + 1];
      float mag = fmaxf(
          fmaxf(fmaxf(fabsf(a0.x), fabsf(a0.y)), fmaxf(fabsf(a0.z), fabsf(a0.w))),
          fmaxf(fmaxf(fabsf(a1.x), fabsf(a1.y)), fmaxf(fabsf(a1.z), fabsf(a1.w))));
      float inv = 1.0f / fmaxf(mag, 1.0f);
      ushort4 o;
      u16* op = (u16*)&o;
#pragma unroll
      for (int j = 0; j < 4; ++j) {
        int h = h0 + j;
        float4 w0 = ((const float4*)a.Wact)[h * 2];
        float4 w1 = ((const float4*)a.Wact)[h * 2 + 1];
        float dot = a0.x * w0.x + a0.y * w0.y + a0.z * w0.z + a0.w * w0.w
                  + a1.x * w1.x + a1.y * w1.y + a1.z * w1.z + a1.w * w1.w;
        op[j] = f2bf(dot * inv + a.bact[h]);
      }
      *(ushort4*)&a.xout[(long)b * 2048 + h0] = o;
    }
  }
}

struct GDesc {
  const u16* A1; const u16* A2;
  int lda1, lda2, K1, K2;
  const u16* W1; const u16* W2;
  int ldw1, ldw2;
  const float* bias;
  float* outF; int ldoF;
  u16* outB; int ldoB;
  int actSilu;
  float* outP;          // fused softmax probs output (nullptr = off)
  const float* bias2;   // per-element f32 bias matrix (nullptr = off)
  int ldb2;
};

// ======== 128x128 2-barrier GEMM, swizzled, desc-select ========
// (256,4): regs <=128 -> 4 blocks/CU, zero tail on 1024-block grids.
// outP: fused per-32-col-group softmax + unimix. bias2: per-element f32 bias.
__global__ __launch_bounds__(256, 4) void gemm128(GDesc d0, GDesc d1) {
  const GDesc d = blockIdx.z ? d1 : d0;
  __shared__ __align__(16) u16 lsA[128 * 64];
  __shared__ __align__(16) u16 lsB[128 * 64];
  const int tid = threadIdx.x;
  const int wave = tid >> 6, lane = tid & 63;
  const int m0 = blockIdx.x * 128, n0 = blockIdx.y * 128;
  const int wr = (wave >> 1) * 64, wc = (wave & 1) * 64;
  const int lrow = lane & 15;
  const int lq = lane >> 4;
  const int lr7 = lrow & 7;
  const int grow = wave * 8 + (lane >> 3);
  const int gcol = ((lane & 7) ^ (lane >> 3)) * 8;
  const int ro0 = ((lq ^ lr7)) * 8;
  const int ro1 = (((4 | lq) ^ lr7)) * 8;

  const f32x4 z4 = {0.f, 0.f, 0.f, 0.f};
  f32x4 acc[4][4];
#pragma unroll
  for (int m = 0; m < 4; ++m)
#pragma unroll
    for (int c = 0; c < 4; ++c) acc[m][c] = z4;

#pragma unroll 1
  for (int phse = 0; phse < 2; ++phse) {
    const u16* A = phse ? d.A2 : d.A1;
    const u16* W = phse ? d.W2 : d.W1;
    const int lda = phse ? d.lda2 : d.lda1;
    const int ldw = phse ? d.ldw2 : d.ldw1;
    const int K = phse ? d.K2 : d.K1;
#pragma unroll 1
    for (int k0 = 0; k0 < K; k0 += 64) {
      __syncthreads();
#pragma unroll
      for (int i = 0; i < 4; ++i) {
        gload16(&A[(long)(m0 + i * 32 + grow) * lda + k0 + gcol], &lsA[i * 2048 + wave * 512]);
        gload16(&W[(long)(n0 + i * 32 + grow) * ldw + k0 + gcol], &lsB[i * 2048 + wave * 512]);
      }
      __syncthreads();
#pragma unroll
      for (int kk = 0; kk < 2; ++kk) {
        const int ro = kk ? ro1 : ro0;
        bf16x8 af[4], wfr[4];
#pragma unroll
        for (int m = 0; m < 4; ++m)
          af[m] = *(const bf16x8*)&lsA[(wr + m * 16 + lrow) * 64 + ro];
#pragma unroll
        for (int c = 0; c < 4; ++c)
          wfr[c] = *(const bf16x8*)&lsB[(wc + c * 16 + lrow) * 64 + ro];
#pragma unroll
        for (int m = 0; m < 4; ++m)
#pragma unroll
          for (int c = 0; c < 4; ++c)
            acc[m][c] = __builtin_amdgcn_mfma_f32_16x16x32_bf16(af[m], wfr[c], acc[m][c], 0, 0, 0);
      }
    }
  }

  if (d.outP) {
    // prior head: write logits + fused softmax(32-col groups) + unimix probs.
    float bv[4];
#pragma unroll
    for (int c = 0; c < 4; ++c) bv[c] = d.bias ? d.bias[n0 + wc + c * 16 + lrow] : 0.f;
#pragma unroll
    for (int m = 0; m < 4; ++m) {
      const int rowb = m0 + wr + m * 16 + lq * 4;
#pragma unroll
      for (int r = 0; r < 4; ++r) {
        const long rb = (long)(rowb + r) * d.ldoF;
        float v[4];
#pragma unroll
        for (int c = 0; c < 4; ++c) {
          v[c] = acc[m][c][r] + bv[c];
          d.outF[rb + n0 + wc + c * 16 + lrow] = v[c];
        }
        // groups: cp=0 -> cols [wc, wc+32) (c=0,1); cp=1 -> [wc+32, wc+64) (c=2,3)
#pragma unroll
        for (int cp = 0; cp < 2; ++cp) {
          float va = v[2 * cp], vb = v[2 * cp + 1];
          float mx = fmaxf(va, vb);
          mx = fmaxf(mx, __shfl_xor(mx, 1));
          mx = fmaxf(mx, __shfl_xor(mx, 2));
          mx = fmaxf(mx, __shfl_xor(mx, 4));
          mx = fmaxf(mx, __shfl_xor(mx, 8));
          float ea = __expf(va - mx), eb = __expf(vb - mx);
          float s = ea + eb;
          s += __shfl_xor(s, 1);
          s += __shfl_xor(s, 2);
          s += __shfl_xor(s, 4);
          s += __shfl_xor(s, 8);
          const float inv = 0.99f / s;
          d.outP[rb + n0 + wc + cp * 32 + lrow]      = ea * inv + 3.125e-4f;
          d.outP[rb + n0 + wc + cp * 32 + 16 + lrow] = eb * inv + 3.125e-4f;
        }
      }
    }
  } else {
#pragma unroll
    for (int c = 0; c < 4; ++c) {
      const int col = n0 + wc + c * 16 + lrow;
      const float bv = d.bias ? d.bias[col] : 0.f;
#pragma unroll
      for (int m = 0; m < 4; ++m) {
        const int rowb = m0 + wr + m * 16 + (lane >> 4) * 4;
#pragma unroll
        for (int r = 0; r < 4; ++r) {
          float v = acc[m][c][r] + bv;
          if (d.bias2) v += d.bias2[(long)(rowb + r) * d.ldb2 + col];
          if (d.actSilu) v = v * sigmoidf_(v);
          if (d.outF) d.outF[(long)(rowb + r) * d.ldoF + col] = v;
          if (d.outB) d.outB[(long)(rowb + r) * d.ldoB + col] = f2bf(v);
        }
      }
    }
  }
}

// ======== block-diagonal GRU gru96: wave = 64 rows x 48 permuted cols ========
// Density 1.71 @ 4 waves/SIMD — measured optimum (R8: 1.5@4w=268us,
// R10: 2.4@2w=248us, this: ~218us). acc 48 AGPR.
__global__ __launch_bounds__(256, 4) void gru96(
    const u16* __restrict__ xbuf, const u16* __restrict__ hbuf,
    const u16* __restrict__ WihP, const u16* __restrict__ WhhP,
    const float* __restrict__ bih, const float* __restrict__ bhh,
    float* __restrict__ outF, u16* __restrict__ hnew)
{
  __shared__ __align__(16) u16 lsA[128 * 64];   // 16 KB
  __shared__ __align__(16) u16 lsW[96 * 64];    // 12 KB
  const int tid = threadIdx.x;
  const int wave = tid >> 6, lane = tid & 63;
  const int wm = wave >> 1;          // 0..1: 64-row half
  const int wn = wave & 1;           // 0..1: 48-col half
  const int m0 = blockIdx.x * 128;
  const int blk = blockIdx.y >> 4;
  const int sp = blockIdx.y & 15;    // 96-permuted-row slice = 32 s-cols
  const int lrow = lane & 15;
  const int lq = lane >> 4;
  const int lr7 = lane & 7;
  const int gcol = ((lane & 7) ^ (lane >> 3)) * 8;
  const int ro0 = ((lq ^ lr7)) * 8;
  const int ro1 = (((4 | lq) ^ lr7)) * 8;

  const f32x4 z4 = {0.f, 0.f, 0.f, 0.f};
  f32x4 acc[4][3];
#pragma unroll
  for (int m = 0; m < 4; ++m)
#pragma unroll
    for (int g = 0; g < 3; ++g) acc[m][g] = z4;

#pragma unroll 1
  for (int phse = 0; phse < 2; ++phse) {
    const u16* A = phse ? (hbuf + blk * 512) : (xbuf + blk * 256);
    const u16* W = phse ? (WhhP + (long)blk * 786432 + sp * 49152)
                        : (WihP + (long)blk * 393216 + sp * 24576);
    const int lda = phse ? 4096 : 2048;
    const int ldw = phse ? 512 : 256;
    const int K = phse ? 512 : 256;
#pragma unroll 1
    for (int k0 = 0; k0 < K; k0 += 64) {
      __syncthreads();
      // A: 128 rows = 16 chunks of 8; 4 waves x 4 rounds
#pragma unroll
      for (int r = 0; r < 4; ++r) {
        const int chunk = r * 4 + wave;
        gload16(&A[(long)(m0 + chunk * 8 + (lane >> 3)) * lda + k0 + gcol], &lsA[chunk * 512]);
      }
      // W: 96 permuted rows = 12 chunks of 8; 4 waves x 3 rounds
#pragma unroll
      for (int r = 0; r < 3; ++r) {
        const int chunk = r * 4 + wave;
        gload16(&W[(long)(chunk * 8 + (lane >> 3)) * ldw + k0 + gcol], &lsW[chunk * 512]);
      }
      __syncthreads();
#pragma unroll
      for (int kk = 0; kk < 2; ++kk) {
        const int ro = kk ? ro1 : ro0;
        bf16x8 af[4], wf[3];
#pragma unroll
        for (int m = 0; m < 4; ++m)
          af[m] = *(const bf16x8*)&lsA[(wm * 64 + m * 16 + lrow) * 64 + ro];
#pragma unroll
        for (int g = 0; g < 3; ++g)
          wf[g] = *(const bf16x8*)&lsW[(wn * 48 + g * 16 + lrow) * 64 + ro];
#pragma unroll
        for (int m = 0; m < 4; ++m)
#pragma unroll
          for (int g = 0; g < 3; ++g)
            acc[m][g] = __builtin_amdgcn_mfma_f32_16x16x32_bf16(af[m], wf[g], acc[m][g], 0, 0, 0);
      }
    }
  }

  // fused GRU epilogue: this thread owns s = sp*32 + wn*16 + lrow
  const int s = sp * 32 + wn * 16 + lrow;
  const int col = blk * 512 + s;
  const long bb = (long)blk * 1536 + s;
  const float br = bih[bb] + bhh[bb];
  const float bu = bih[bb + 512] + bhh[bb + 512];
  const float bc = bih[bb + 1024] + bhh[bb + 1024];
#pragma unroll
  for (int m = 0; m < 4; ++m) {
    const int rowb = m0 + wm * 64 + m * 16 + lq * 4;
#pragma unroll
    for (int r = 0; r < 4; ++r) {
      const int row = rowb + r;
      const float gr = acc[m][0][r] + br;
      const float gu = acc[m][1][r] + bu;
      const float gc = acc[m][2][r] + bc;
      const float rr = sigmoidf_(gr);
      const float uu = sigmoidf_(gu);
      const float cand = tanhf_(rr * gc);
      const float h = bf2f(hbuf[(long)row * 4096 + col]);
      const float hn = (1.f - uu) * h + uu * cand;
      outF[(long)row * OUTLD + col] = hn;
      hnew[(long)row * 4096 + col] = f2bf(hn);
    }
  }
}

extern "C" void kernel_launch(void* const* d_in, const int* in_sizes, int n_in,
                              void* d_out, int out_size, void* d_ws, size_t ws_size,
                              hipStream_t stream) {
  const float* det   = (const float*)d_in[0];
  const float* stoch = (const float*)d_in[1];
  const float* pact  = (const float*)d_in[2];
  const float* embed = (const float*)d_in[3];
  const void*  isf   = d_in[4];
  const float* Wact  = (const float*)d_in[5];
  const float* bact  = (const float*)d_in[6];
  const float* Wst   = (const float*)d_in[7];
  const float* bst   = (const float*)d_in[8];
  const float* Wih   = (const float*)d_in[9];
  const float* bih   = (const float*)d_in[10];
  const float* Whh   = (const float*)d_in[11];
  const float* bhh   = (const float*)d_in[12];
  const float* Wpr1  = (const float*)d_in[13];
  const float* bpr1  = (const float*)d_in[14];
  const float* Wpr2  = (const float*)d_in[15];
  const float* bpr2  = (const float*)d_in[16];
  const float* Wpo1  = (const float*)d_in[17];
  const float* bpo1  = (const float*)d_in[18];
  const float* Wpo2  = (const float*)d_in[19];
  const float* bpo2  = (const float*)d_in[20];
  float* out = (float*)d_out;

  u16* wsu  = (u16*)((char*)d_ws + 256);
  u16* bWst  = wsu;                   // 1,048,576
  u16* bWihP = wsu + 1048576UL;       // 3,145,728 (permuted)
  u16* bWhhP = wsu + 4194304UL;       // 6,291,456 (permuted)
  u16* bWpr1 = wsu + 10485760UL;      // 4,194,304
  u16* bWpr2 = wsu + 14680064UL;      // 1,048,576
  u16* bWpo1 = wsu + 15728640UL;      // 5,242,880
  u16* bWpo2 = wsu + 20971520UL;      // 1,048,576
  u16* bufX  = wsu + 22020096UL;      // 16,777,216  [B,2048]
  u16* bufSt = wsu + 38797312UL;      // 8,388,608   stoch -> later ph
  u16* bufHb = wsu + 47185920UL;      // 33,554,432  hb -> later qh
  u16* bufHn = wsu + 80740352UL;      // 33,554,432  h_new bf16
  u16* bufEm = wsu + 114294784UL;     // 8,388,608   embed bf16

  FuseArgs fa;
  fa.cs[0] = Wst;  fa.cd[0] = bWst;  fa.cn[0] = 262144L;
  fa.cs[1] = Wpr1; fa.cd[1] = bWpr1; fa.cn[1] = 1048576L;
  fa.cs[2] = Wpr2; fa.cd[2] = bWpr2; fa.cn[2] = 262144L;
  fa.cs[3] = Wpo1; fa.cd[3] = bWpo1; fa.cn[3] = 1310720L;
  fa.cs[4] = Wpo2; fa.cd[4] = bWpo2; fa.cn[4] = 262144L;
  fa.sIh = Wih; fa.dIh = bWihP; fa.sHh = Whh; fa.dHh = bWhhP;
  fa.ps[0] = stoch; fa.pd[0] = bufSt; fa.pn[0] = 2097152L; fa.pc4[0] = 256;  fa.pdoR[0] = 1;
  fa.ps[1] = det;   fa.pd[1] = bufHb; fa.pn[1] = 8388608L; fa.pc4[1] = 1024; fa.pdoR[1] = 1;
  fa.ps[2] = embed; fa.pd[2] = bufEm; fa.pn[2] = 2097152L; fa.pc4[2] = 256;  fa.pdoR[2] = 0;
  fa.act = pact; fa.Wact = Wact; fa.bact = bact; fa.xout = bufX;
  fa.isf = isf;
  k_fuse<<<dim3(4096), dim3(256), 0, stream>>>(fa);

  // se (z=0) + embAcc = embed @ Wpo1[:,4096:]^T + bpo1 (z=1, parked in out[:,4096:5120))
  GDesc dSe, dEmb;
  dSe.A1 = bufSt; dSe.A2 = nullptr; dSe.lda1 = 1024; dSe.lda2 = 0;
  dSe.K1 = 1024; dSe.K2 = 0;
  dSe.W1 = bWst; dSe.W2 = nullptr; dSe.ldw1 = 1024; dSe.ldw2 = 0;
  dSe.bias = bst; dSe.outF = nullptr; dSe.ldoF = 0;
  dSe.outB = bufX + 1024; dSe.ldoB = 2048; dSe.actSilu = 0; dSe.outP = nullptr;
  dSe.bias2 = nullptr; dSe.ldb2 = 0;
  dEmb.A1 = bufEm; dEmb.A2 = nullptr; dEmb.lda1 = 1024; dEmb.lda2 = 0;
  dEmb.K1 = 1024; dEmb.K2 = 0;
  dEmb.W1 = bWpo1 + 4096; dEmb.W2 = nullptr; dEmb.ldw1 = 5120; dEmb.ldw2 = 0;
  dEmb.bias = bpo1; dEmb.outF = out + 4096; dEmb.ldoF = OUTLD;
  dEmb.outB = nullptr; dEmb.ldoB = 0; dEmb.actSilu = 0; dEmb.outP = nullptr;
  dEmb.bias2 = nullptr; dEmb.ldb2 = 0;
  gemm128<<<dim3(64, 8, 2), dim3(256), 0, stream>>>(dSe, dEmb);

  // GRU -> h_new (f32 to out cols [0,4096), bf16 to ws)
  gru96<<<dim3(64, 128), dim3(256), 0, stream>>>(bufX, bufHb, bWihP, bWhhP,
                                                 bih, bhh, out, bufHn);

  // pr1 + po1 merged (z-desc); po1 K-balanced: embed phase pre-hoisted to embAcc
  GDesc dPr1, dPo1;
  dPr1.A1 = bufHn; dPr1.A2 = nullptr; dPr1.lda1 = 4096; dPr1.lda2 = 0;
  dPr1.K1 = 4096; dPr1.K2 = 0;
  dPr1.W1 = bWpr1; dPr1.W2 = nullptr; dPr1.ldw1 = 4096; dPr1.ldw2 = 0;
  dPr1.bias = bpr1; dPr1.outF = nullptr; dPr1.ldoF = 0;
  dPr1.outB = bufSt; dPr1.ldoB = 1024; dPr1.actSilu = 1; dPr1.outP = nullptr;
  dPr1.bias2 = nullptr; dPr1.ldb2 = 0;
  dPo1.A1 = bufHn; dPo1.A2 = nullptr; dPo1.lda1 = 4096; dPo1.lda2 = 0;
  dPo1.K1 = 4096; dPo1.K2 = 0;
  dPo1.W1 = bWpo1; dPo1.W2 = nullptr; dPo1.ldw1 = 5120; dPo1.ldw2 = 0;
  dPo1.bias = nullptr; dPo1.outF = nullptr; dPo1.ldoF = 0;
  dPo1.outB = bufHb; dPo1.ldoB = 1024; dPo1.actSilu = 1; dPo1.outP = nullptr;
  dPo1.bias2 = out + 4096; dPo1.ldb2 = OUTLD;
  gemm128<<<dim3(64, 8, 2), dim3(256), 0, stream>>>(dPr1, dPo1);

  // pr2 (+fused softmax/unimix, overwrites embAcc region) + po2 merged (z-desc)
  GDesc dPr2, dPo2;
  dPr2.A1 = bufSt; dPr2.A2 = nullptr; dPr2.lda1 = 1024; dPr2.lda2 = 0;
  dPr2.K1 = 1024; dPr2.K2 = 0;
  dPr2.W1 = bWpr2; dPr2.W2 = nullptr; dPr2.ldw1 = 1024; dPr2.ldw2 = 0;
  dPr2.bias = bpr2; dPr2.outF = out + 4096; dPr2.ldoF = OUTLD;
  dPr2.outB = nullptr; dPr2.ldoB = 0; dPr2.actSilu = 0;
  dPr2.outP = out + 5120; dPr2.bias2 = nullptr; dPr2.ldb2 = 0;
  dPo2.A1 = bufHb; dPo2.A2 = nullptr; dPo2.lda1 = 1024; dPo2.lda2 = 0;
  dPo2.K1 = 1024; dPo2.K2 = 0;
  dPo2.W1 = bWpo2; dPo2.W2 = nullptr; dPo2.ldw1 = 1024; dPo2.ldw2 = 0;
  dPo2.bias = bpo2; dPo2.outF = out + 6144; dPo2.ldoF = OUTLD;
  dPo2.outB = nullptr; dPo2.ldoB = 0; dPo2.actSilu = 0; dPo2.outP = nullptr;
  dPo2.bias2 = nullptr; dPo2.ldb2 = 0;
  gemm128<<<dim3(64, 8, 2), dim3(256), 0, stream>>>(dPr2, dPo2);
}

// Round 15
// 607.667 us; speedup vs baseline: 1.0550x; 1.0550x over previous
//
#include <hip/hip_runtime.h>

typedef unsigned short u16;
typedef short bf16x8 __attribute__((ext_vector_type(8)));
typedef float f32x4 __attribute__((ext_vector_type(4)));

#define BSZ 8192
#define OUTLD 7168

__device__ __forceinline__ u16 f2bf(float f) {
  union { float f; unsigned u; } v; v.f = f;
  unsigned r = v.u + 0x7FFFu + ((v.u >> 16) & 1u);
  return (u16)(r >> 16);
}
__device__ __forceinline__ float bf2f(u16 h) {
  union { unsigned u; float f; } v; v.u = ((unsigned)h) << 16;
  return v.f;
}
__device__ __forceinline__ float sigmoidf_(float x) { return 1.0f / (1.0f + __expf(-x)); }
__device__ __forceinline__ float tanhf_(float t) { return 2.0f / (1.0f + __expf(-2.0f * t)) - 1.0f; }

__device__ __forceinline__ void gload16(const u16* g, u16* l) {
  __builtin_amdgcn_global_load_lds(
      (const __attribute__((address_space(1))) void*)g,
      (__attribute__((address_space(3))) void*)l, 16, 0, 0);
}

// ======== fused front-end: weight cvt + gru perm-cvt + input prep + ae ========
struct FuseArgs {
  const float* cs[5]; u16* cd[5]; long cn[5];          // plain cvt segments (float4 units)
  const float* sIh; u16* dIh; const float* sHh; u16* dHh;
  const float* ps[3]; u16* pd[3]; long pn[3]; int pc4[3]; int pdoR[3];
  const float* act; const float* Wact; const float* bact; u16* xout;
  const void* isf;
};

__global__ void k_fuse(FuseArgs a) {
  // inline is_first dtype detect (bool8 vs int32/f32), 8KB scan per block (L2-hot)
  __shared__ unsigned redS;
  if (threadIdx.x == 0) redS = 0u;
  __syncthreads();
  {
    unsigned v = 0;
    const unsigned* w = (const unsigned*)a.isf;
    for (int i = threadIdx.x; i < 2048; i += 256) v |= w[i];
    atomicOr(&redS, v);
  }
  __syncthreads();
  const int fl = (((redS & 0xFFFFFF00u) != 0u) && ((redS & 0xFEFEFEFEu) == 0u)) ? 1 : 0;

  const long B0 = 3145728L;                 // end cvtW
  const long B1 = B0 + 1179648L;            // end gruW (8-elem units)
  const long B2 = B1 + 12582912L;           // end prep (float4 units)
  const long B3 = B2 + 2097152L;            // end ae (4-h units)
  const long nIh = 393216L;

  long stride = (long)gridDim.x * blockDim.x;
  for (long i = blockIdx.x * (long)blockDim.x + threadIdx.x; i < B3; i += stride) {
    if (i < B0) {
      long rem = i; int k = 0;
      while (k < 4 && rem >= a.cn[k]) { rem -= a.cn[k]; ++k; }
      float4 v = ((const float4*)a.cs[k])[rem];
      ushort4 o; o.x = f2bf(v.x); o.y = f2bf(v.y); o.z = f2bf(v.z); o.w = f2bf(v.w);
      ((ushort4*)a.cd[k])[rem] = o;
    } else if (i < B1) {
      long rel = i - B0;
      const float* src; u16* dst; int ldk;
      if (rel < nIh) { src = a.sIh; dst = a.dIh; ldk = 256; }
      else           { src = a.sHh; dst = a.dHh; ldk = 512; rel -= nIh; }
      int kc = ldk >> 3;
      int j = (int)(rel % kc); long row = rel / kc;
      long blk = row / 1536; int rP = (int)(row % 1536);
      int sHi = rP / 48, rem = rP % 48, g = rem >> 4, sLo = rem & 15;
      int srow = g * 512 + sHi * 16 + sLo;
      const float* s = src + (blk * 1536 + srow) * (long)ldk + j * 8;
      float4 v0 = ((const float4*)s)[0], v1 = ((const float4*)s)[1];
      ushort4 o0; o0.x = f2bf(v0.x); o0.y = f2bf(v0.y); o0.z = f2bf(v0.z); o0.w = f2bf(v0.w);
      ushort4 o1; o1.x = f2bf(v1.x); o1.y = f2bf(v1.y); o1.z = f2bf(v1.z); o1.w = f2bf(v1.w);
      ((ushort4*)(dst + rel * 8))[0] = o0;
      ((ushort4*)(dst + rel * 8))[1] = o1;
    } else if (i < B2) {
      long rel = i - B1; int k = 0;
      while (k < 2 && rel >= a.pn[k]) { rel -= a.pn[k]; ++k; }
      float4 v = ((const float4*)a.ps[k])[rel];
      if (a.pdoR[k]) {
        int b = (int)(rel / a.pc4[k]);
        bool isf1 = fl ? (((const unsigned char*)a.isf)[b] != 0)
                       : (((const int*)a.isf)[b] != 0);
        if (isf1) { v.x = v.y = v.z = v.w = 0.f; }
      }
      ushort4 o; o.x = f2bf(v.x); o.y = f2bf(v.y); o.z = f2bf(v.z); o.w = f2bf(v.w);
      ((ushort4*)a.pd[k])[rel] = o;
    } else {
      long t = i - B2;
      int b = (int)(t >> 8), h0 = (int)(t & 255) * 4;
      float4 a0 = ((const float4*)a.act)[b * 2];
      float4 a1 = ((const float4*)a.act)[b * 2 + 1];
      float mag = fmaxf(
          fmaxf(fmaxf(fabsf(a0.x), fabsf(a0.y)), fmaxf(fabsf(a0.z), fabsf(a0.w))),
          fmaxf(fmaxf(fabsf(a1.x), fabsf(a1.y)), fmaxf(fabsf(a1.z), fabsf(a1.w))));
      float inv = 1.0f / fmaxf(mag, 1.0f);
      ushort4 o;
      u16* op = (u16*)&o;
#pragma unroll
      for (int j = 0; j < 4; ++j) {
        int h = h0 + j;
        float4 w0 = ((const float4*)a.Wact)[h * 2];
        float4 w1 = ((const float4*)a.Wact)[h * 2 + 1];
        float dot = a0.x * w0.x + a0.y * w0.y + a0.z * w0.z + a0.w * w0.w
                  + a1.x * w1.x + a1.y * w1.y + a1.z * w1.z + a1.w * w1.w;
        op[j] = f2bf(dot * inv + a.bact[h]);
      }
      *(ushort4*)&a.xout[(long)b * 2048 + h0] = o;
    }
  }
}

struct GDesc {
  const u16* A1; const u16* A2;
  int lda1, lda2, K1, K2;
  const u16* W1; const u16* W2;
  int ldw1, ldw2;
  const float* bias;
  float* outF; int ldoF;
  u16* outB; int ldoB;
  int actSilu;
  float* outP;          // fused softmax probs output (nullptr = off)
};

// ======== 128x128 2-barrier GEMM, swizzled, desc-select ========
// (256,4): regs <=128 -> 4 blocks/CU, zero tail on 1024-block grids.
// outP path: fused per-32-col-group softmax + unimix (prior head).
__global__ __launch_bounds__(256, 4) void gemm128(GDesc d0, GDesc d1) {
  const GDesc d = blockIdx.z ? d1 : d0;
  __shared__ __align__(16) u16 lsA[128 * 64];
  __shared__ __align__(16) u16 lsB[128 * 64];
  const int tid = threadIdx.x;
  const int wave = tid >> 6, lane = tid & 63;
  const int m0 = blockIdx.x * 128, n0 = blockIdx.y * 128;
  const int wr = (wave >> 1) * 64, wc = (wave & 1) * 64;
  const int lrow = lane & 15;
  const int lq = lane >> 4;
  const int lr7 = lrow & 7;
  const int grow = wave * 8 + (lane >> 3);
  const int gcol = ((lane & 7) ^ (lane >> 3)) * 8;
  const int ro0 = ((lq ^ lr7)) * 8;
  const int ro1 = (((4 | lq) ^ lr7)) * 8;

  const f32x4 z4 = {0.f, 0.f, 0.f, 0.f};
  f32x4 acc[4][4];
#pragma unroll
  for (int m = 0; m < 4; ++m)
#pragma unroll
    for (int c = 0; c < 4; ++c) acc[m][c] = z4;

#pragma unroll 1
  for (int phse = 0; phse < 2; ++phse) {
    const u16* A = phse ? d.A2 : d.A1;
    const u16* W = phse ? d.W2 : d.W1;
    const int lda = phse ? d.lda2 : d.lda1;
    const int ldw = phse ? d.ldw2 : d.ldw1;
    const int K = phse ? d.K2 : d.K1;
#pragma unroll 1
    for (int k0 = 0; k0 < K; k0 += 64) {
      __syncthreads();
#pragma unroll
      for (int i = 0; i < 4; ++i) {
        gload16(&A[(long)(m0 + i * 32 + grow) * lda + k0 + gcol], &lsA[i * 2048 + wave * 512]);
        gload16(&W[(long)(n0 + i * 32 + grow) * ldw + k0 + gcol], &lsB[i * 2048 + wave * 512]);
      }
      __syncthreads();
#pragma unroll
      for (int kk = 0; kk < 2; ++kk) {
        const int ro = kk ? ro1 : ro0;
        bf16x8 af[4], wfr[4];
#pragma unroll
        for (int m = 0; m < 4; ++m)
          af[m] = *(const bf16x8*)&lsA[(wr + m * 16 + lrow) * 64 + ro];
#pragma unroll
        for (int c = 0; c < 4; ++c)
          wfr[c] = *(const bf16x8*)&lsB[(wc + c * 16 + lrow) * 64 + ro];
#pragma unroll
        for (int m = 0; m < 4; ++m)
#pragma unroll
          for (int c = 0; c < 4; ++c)
            acc[m][c] = __builtin_amdgcn_mfma_f32_16x16x32_bf16(af[m], wfr[c], acc[m][c], 0, 0, 0);
      }
    }
  }

  if (d.outP) {
    // prior head: write logits + fused softmax(32-col groups) + unimix probs.
    float bv[4];
#pragma unroll
    for (int c = 0; c < 4; ++c) bv[c] = d.bias ? d.bias[n0 + wc + c * 16 + lrow] : 0.f;
#pragma unroll
    for (int m = 0; m < 4; ++m) {
      const int rowb = m0 + wr + m * 16 + lq * 4;
#pragma unroll
      for (int r = 0; r < 4; ++r) {
        const long rb = (long)(rowb + r) * d.ldoF;
        float v[4];
#pragma unroll
        for (int c = 0; c < 4; ++c) {
          v[c] = acc[m][c][r] + bv[c];
          d.outF[rb + n0 + wc + c * 16 + lrow] = v[c];
        }
        // groups: cp=0 -> cols [wc, wc+32) (c=0,1); cp=1 -> [wc+32, wc+64) (c=2,3)
#pragma unroll
        for (int cp = 0; cp < 2; ++cp) {
          float va = v[2 * cp], vb = v[2 * cp + 1];
          float mx = fmaxf(va, vb);
          mx = fmaxf(mx, __shfl_xor(mx, 1));
          mx = fmaxf(mx, __shfl_xor(mx, 2));
          mx = fmaxf(mx, __shfl_xor(mx, 4));
          mx = fmaxf(mx, __shfl_xor(mx, 8));
          float ea = __expf(va - mx), eb = __expf(vb - mx);
          float s = ea + eb;
          s += __shfl_xor(s, 1);
          s += __shfl_xor(s, 2);
          s += __shfl_xor(s, 4);
          s += __shfl_xor(s, 8);
          const float inv = 0.99f / s;
          d.outP[rb + n0 + wc + cp * 32 + lrow]      = ea * inv + 3.125e-4f;
          d.outP[rb + n0 + wc + cp * 32 + 16 + lrow] = eb * inv + 3.125e-4f;
        }
      }
    }
  } else {
#pragma unroll
    for (int c = 0; c < 4; ++c) {
      const int col = n0 + wc + c * 16 + lrow;
      const float bv = d.bias ? d.bias[col] : 0.f;
#pragma unroll
      for (int m = 0; m < 4; ++m) {
        const int rowb = m0 + wr + m * 16 + (lane >> 4) * 4;
#pragma unroll
        for (int r = 0; r < 4; ++r) {
          float v = acc[m][c][r] + bv;
          if (d.actSilu) v = v * sigmoidf_(v);
          if (d.outF) d.outF[(long)(rowb + r) * d.ldoF + col] = v;
          if (d.outB) d.outB[(long)(rowb + r) * d.ldoB + col] = f2bf(v);
        }
      }
    }
  }
}

// ======== block-diagonal GRU gru96: wave = 64 rows x 48 permuted cols ========
// Density 1.71 @ 4 waves/SIMD — measured optimum (R8: 1.5@4w=268us,
// R10: 2.4@2w=248us, this: ~218us). acc 48 AGPR.
__global__ __launch_bounds__(256, 4) void gru96(
    const u16* __restrict__ xbuf, const u16* __restrict__ hbuf,
    const u16* __restrict__ WihP, const u16* __restrict__ WhhP,
    const float* __restrict__ bih, const float* __restrict__ bhh,
    float* __restrict__ outF, u16* __restrict__ hnew)
{
  __shared__ __align__(16) u16 lsA[128 * 64];   // 16 KB
  __shared__ __align__(16) u16 lsW[96 * 64];    // 12 KB
  const int tid = threadIdx.x;
  const int wave = tid >> 6, lane = tid & 63;
  const int wm = wave >> 1;          // 0..1: 64-row half
  const int wn = wave & 1;           // 0..1: 48-col half
  const int m0 = blockIdx.x * 128;
  const int blk = blockIdx.y >> 4;
  const int sp = blockIdx.y & 15;    // 96-permuted-row slice = 32 s-cols
  const int lrow = lane & 15;
  const int lq = lane >> 4;
  const int lr7 = lane & 7;
  const int gcol = ((lane & 7) ^ (lane >> 3)) * 8;
  const int ro0 = ((lq ^ lr7)) * 8;
  const int ro1 = (((4 | lq) ^ lr7)) * 8;

  const f32x4 z4 = {0.f, 0.f, 0.f, 0.f};
  f32x4 acc[4][3];
#pragma unroll
  for (int m = 0; m < 4; ++m)
#pragma unroll
    for (int g = 0; g < 3; ++g) acc[m][g] = z4;

#pragma unroll 1
  for (int phse = 0; phse < 2; ++phse) {
    const u16* A = phse ? (hbuf + blk * 512) : (xbuf + blk * 256);
    const u16* W = phse ? (WhhP + (long)blk * 786432 + sp * 49152)
                        : (WihP + (long)blk * 393216 + sp * 24576);
    const int lda = phse ? 4096 : 2048;
    const int ldw = phse ? 512 : 256;
    const int K = phse ? 512 : 256;
#pragma unroll 1
    for (int k0 = 0; k0 < K; k0 += 64) {
      __syncthreads();
      // A: 128 rows = 16 chunks of 8; 4 waves x 4 rounds
#pragma unroll
      for (int r = 0; r < 4; ++r) {
        const int chunk = r * 4 + wave;
        gload16(&A[(long)(m0 + chunk * 8 + (lane >> 3)) * lda + k0 + gcol], &lsA[chunk * 512]);
      }
      // W: 96 permuted rows = 12 chunks of 8; 4 waves x 3 rounds
#pragma unroll
      for (int r = 0; r < 3; ++r) {
        const int chunk = r * 4 + wave;
        gload16(&W[(long)(chunk * 8 + (lane >> 3)) * ldw + k0 + gcol], &lsW[chunk * 512]);
      }
      __syncthreads();
#pragma unroll
      for (int kk = 0; kk < 2; ++kk) {
        const int ro = kk ? ro1 : ro0;
        bf16x8 af[4], wf[3];
#pragma unroll
        for (int m = 0; m < 4; ++m)
          af[m] = *(const bf16x8*)&lsA[(wm * 64 + m * 16 + lrow) * 64 + ro];
#pragma unroll
        for (int g = 0; g < 3; ++g)
          wf[g] = *(const bf16x8*)&lsW[(wn * 48 + g * 16 + lrow) * 64 + ro];
#pragma unroll
        for (int m = 0; m < 4; ++m)
#pragma unroll
          for (int g = 0; g < 3; ++g)
            acc[m][g] = __builtin_amdgcn_mfma_f32_16x16x32_bf16(af[m], wf[g], acc[m][g], 0, 0, 0);
      }
    }
  }

  // fused GRU epilogue: this thread owns s = sp*32 + wn*16 + lrow
  const int s = sp * 32 + wn * 16 + lrow;
  const int col = blk * 512 + s;
  const long bb = (long)blk * 1536 + s;
  const float br = bih[bb] + bhh[bb];
  const float bu = bih[bb + 512] + bhh[bb + 512];
  const float bc = bih[bb + 1024] + bhh[bb + 1024];
#pragma unroll
  for (int m = 0; m < 4; ++m) {
    const int rowb = m0 + wm * 64 + m * 16 + lq * 4;
#pragma unroll
    for (int r = 0; r < 4; ++r) {
      const int row = rowb + r;
      const float gr = acc[m][0][r] + br;
      const float gu = acc[m][1][r] + bu;
      const float gc = acc[m][2][r] + bc;
      const float rr = sigmoidf_(gr);
      const float uu = sigmoidf_(gu);
      const float cand = tanhf_(rr * gc);
      const float h = bf2f(hbuf[(long)row * 4096 + col]);
      const float hn = (1.f - uu) * h + uu * cand;
      outF[(long)row * OUTLD + col] = hn;
      hnew[(long)row * 4096 + col] = f2bf(hn);
    }
  }
}

extern "C" void kernel_launch(void* const* d_in, const int* in_sizes, int n_in,
                              void* d_out, int out_size, void* d_ws, size_t ws_size,
                              hipStream_t stream) {
  const float* det   = (const float*)d_in[0];
  const float* stoch = (const float*)d_in[1];
  const float* pact  = (const float*)d_in[2];
  const float* embed = (const float*)d_in[3];
  const void*  isf   = d_in[4];
  const float* Wact  = (const float*)d_in[5];
  const float* bact  = (const float*)d_in[6];
  const float* Wst   = (const float*)d_in[7];
  const float* bst   = (const float*)d_in[8];
  const float* Wih   = (const float*)d_in[9];
  const float* bih   = (const float*)d_in[10];
  const float* Whh   = (const float*)d_in[11];
  const float* bhh   = (const float*)d_in[12];
  const float* Wpr1  = (const float*)d_in[13];
  const float* bpr1  = (const float*)d_in[14];
  const float* Wpr2  = (const float*)d_in[15];
  const float* bpr2  = (const float*)d_in[16];
  const float* Wpo1  = (const float*)d_in[17];
  const float* bpo1  = (const float*)d_in[18];
  const float* Wpo2  = (const float*)d_in[19];
  const float* bpo2  = (const float*)d_in[20];
  float* out = (float*)d_out;

  u16* wsu  = (u16*)((char*)d_ws + 256);
  u16* bWst  = wsu;                   // 1,048,576
  u16* bWihP = wsu + 1048576UL;       // 3,145,728 (permuted)
  u16* bWhhP = wsu + 4194304UL;       // 6,291,456 (permuted)
  u16* bWpr1 = wsu + 10485760UL;      // 4,194,304
  u16* bWpr2 = wsu + 14680064UL;      // 1,048,576
  u16* bWpo1 = wsu + 15728640UL;      // 5,242,880
  u16* bWpo2 = wsu + 20971520UL;      // 1,048,576
  u16* bufX  = wsu + 22020096UL;      // 16,777,216  [B,2048]
  u16* bufSt = wsu + 38797312UL;      // 8,388,608   stoch -> later ph
  u16* bufHb = wsu + 47185920UL;      // 33,554,432  hb -> later qh
  u16* bufHn = wsu + 80740352UL;      // 33,554,432  h_new bf16
  u16* bufEm = wsu + 114294784UL;     // 8,388,608   embed bf16

  FuseArgs fa;
  fa.cs[0] = Wst;  fa.cd[0] = bWst;  fa.cn[0] = 262144L;
  fa.cs[1] = Wpr1; fa.cd[1] = bWpr1; fa.cn[1] = 1048576L;
  fa.cs[2] = Wpr2; fa.cd[2] = bWpr2; fa.cn[2] = 262144L;
  fa.cs[3] = Wpo1; fa.cd[3] = bWpo1; fa.cn[3] = 1310720L;
  fa.cs[4] = Wpo2; fa.cd[4] = bWpo2; fa.cn[4] = 262144L;
  fa.sIh = Wih; fa.dIh = bWihP; fa.sHh = Whh; fa.dHh = bWhhP;
  fa.ps[0] = stoch; fa.pd[0] = bufSt; fa.pn[0] = 2097152L; fa.pc4[0] = 256;  fa.pdoR[0] = 1;
  fa.ps[1] = det;   fa.pd[1] = bufHb; fa.pn[1] = 8388608L; fa.pc4[1] = 1024; fa.pdoR[1] = 1;
  fa.ps[2] = embed; fa.pd[2] = bufEm; fa.pn[2] = 2097152L; fa.pc4[2] = 256;  fa.pdoR[2] = 0;
  fa.act = pact; fa.Wact = Wact; fa.bact = bact; fa.xout = bufX;
  fa.isf = isf;
  k_fuse<<<dim3(4096), dim3(256), 0, stream>>>(fa);

  // se = stoch @ Wst^T + b -> x[:, 1024:2048]
  GDesc dSe;
  dSe.A1 = bufSt; dSe.A2 = nullptr; dSe.lda1 = 1024; dSe.lda2 = 0;
  dSe.K1 = 1024; dSe.K2 = 0;
  dSe.W1 = bWst; dSe.W2 = nullptr; dSe.ldw1 = 1024; dSe.ldw2 = 0;
  dSe.bias = bst; dSe.outF = nullptr; dSe.ldoF = 0;
  dSe.outB = bufX + 1024; dSe.ldoB = 2048; dSe.actSilu = 0; dSe.outP = nullptr;
  gemm128<<<dim3(64, 8, 1), dim3(256), 0, stream>>>(dSe, dSe);

  // GRU -> h_new (f32 to out cols [0,4096), bf16 to ws)
  gru96<<<dim3(64, 128), dim3(256), 0, stream>>>(bufX, bufHb, bWihP, bWhhP,
                                                 bih, bhh, out, bufHn);

  // pr1 + po1 merged (z-desc)
  GDesc dPr1, dPo1;
  dPr1.A1 = bufHn; dPr1.A2 = nullptr; dPr1.lda1 = 4096; dPr1.lda2 = 0;
  dPr1.K1 = 4096; dPr1.K2 = 0;
  dPr1.W1 = bWpr1; dPr1.W2 = nullptr; dPr1.ldw1 = 4096; dPr1.ldw2 = 0;
  dPr1.bias = bpr1; dPr1.outF = nullptr; dPr1.ldoF = 0;
  dPr1.outB = bufSt; dPr1.ldoB = 1024; dPr1.actSilu = 1; dPr1.outP = nullptr;
  dPo1.A1 = bufHn; dPo1.A2 = bufEm; dPo1.lda1 = 4096; dPo1.lda2 = 1024;
  dPo1.K1 = 4096; dPo1.K2 = 1024;
  dPo1.W1 = bWpo1; dPo1.W2 = bWpo1 + 4096; dPo1.ldw1 = 5120; dPo1.ldw2 = 5120;
  dPo1.bias = bpo1; dPo1.outF = nullptr; dPo1.ldoF = 0;
  dPo1.outB = bufHb; dPo1.ldoB = 1024; dPo1.actSilu = 1; dPo1.outP = nullptr;
  gemm128<<<dim3(64, 8, 2), dim3(256), 0, stream>>>(dPr1, dPo1);

  // pr2 (+fused softmax/unimix) + po2 merged (z-desc)
  GDesc dPr2, dPo2;
  dPr2.A1 = bufSt; dPr2.A2 = nullptr; dPr2.lda1 = 1024; dPr2.lda2 = 0;
  dPr2.K1 = 1024; dPr2.K2 = 0;
  dPr2.W1 = bWpr2; dPr2.W2 = nullptr; dPr2.ldw1 = 1024; dPr2.ldw2 = 0;
  dPr2.bias = bpr2; dPr2.outF = out + 4096; dPr2.ldoF = OUTLD;
  dPr2.outB = nullptr; dPr2.ldoB = 0; dPr2.actSilu = 0;
  dPr2.outP = out + 5120;
  dPo2.A1 = bufHb; dPo2.A2 = nullptr; dPo2.lda1 = 1024; dPo2.lda2 = 0;
  dPo2.K1 = 1024; dPo2.K2 = 0;
  dPo2.W1 = bWpo2; dPo2.W2 = nullptr; dPo2.ldw1 = 1024; dPo2.ldw2 = 0;
  dPo2.bias = bpo2; dPo2.outF = out + 6144; dPo2.ldoF = OUTLD;
  dPo2.outB = nullptr; dPo2.ldoB = 0; dPo2.actSilu = 0; dPo2.outP = nullptr;
  gemm128<<<dim3(64, 8, 2), dim3(256), 0, stream>>>(dPr2, dPo2);
}